// Round 17
// baseline (248.255 us; speedup 1.0000x reference)
//
#include <hip/hip_runtime.h>

typedef __bf16 bf16x8 __attribute__((ext_vector_type(8)));
typedef float f32x4 __attribute__((ext_vector_type(4)));

__device__ __forceinline__ unsigned short f2bf(float f) {
    unsigned int u = __builtin_bit_cast(unsigned int, f);
    u += 0x7fffu + ((u >> 16) & 1u);
    return (unsigned short)(u >> 16);
}
__device__ __forceinline__ float bf2f(unsigned short u) {
    return __builtin_bit_cast(float, (unsigned)u << 16);
}

// XOR swizzle for 1024B-row LDS tiles: byte ^= ((row&7)<<4)
__device__ __forceinline__ unsigned swz1k(unsigned byte) {
    return byte ^ ((byte >> 6) & 0x70u);
}

// Raw barrier: LDS-visibility only; does NOT drain vmcnt.
__device__ __forceinline__ void bar_lgkm() {
    asm volatile("s_waitcnt lgkmcnt(0)\n\ts_barrier" ::: "memory");
}
#define SB() __builtin_amdgcn_sched_barrier(0)

// ---------------- K1: Pc[kc][j][t] = M[kc*32+t][j], M = Wq^T Wk  (bf16)
// plus Wv -> bf16 copy.
__global__ __launch_bounds__(256) void prep_kernel(
    const float* __restrict__ Wq, const float* __restrict__ Wk,
    const float* __restrict__ Wv, unsigned short* __restrict__ Pc,
    unsigned short* __restrict__ Wvb)
{
    int b = blockIdx.x;
    if (b < 1024) {
        int j0 = (b >> 4) * 8;
        int kc = b & 15;
        int jloc = threadIdx.x >> 5;
        int t = threadIdx.x & 31;
        int j = j0 + jloc, d = kc * 32 + t;
        float acc = 0.f;
        #pragma unroll 8
        for (int e = 0; e < 512; ++e)
            acc = fmaf(Wk[e * 512 + j], Wq[e * 512 + d], acc);
        Pc[((kc * 512) + j) * 32 + t] = f2bf(acc);
    } else {
        int i = (b - 1024) * 256 + (int)threadIdx.x;
        Wvb[i] = f2bf(Wv[i]);
    }
}

// issue H column-quarter q (64-row tile, 1024 threads): 2 float4/thread.
__device__ __forceinline__ void issue_q(int q, int tid, const float4* hsrc, float4 (&hq)[2]) {
    #pragma unroll
    for (int r = 0; r < 2; ++r) {
        int flat = r * 1024 + tid;         // [0,2048)
        hq[r] = hsrc[(flat >> 5) * 128 + q * 32 + (flat & 31)];
    }
}

// convert quarter q -> bf16 swizzled HBF (consumes hq)
__device__ __forceinline__ void convert_q(int q, int tid, char* HBF, float4 (&hq)[2]) {
    #pragma unroll
    for (int r = 0; r < 2; ++r) {
        int flat = r * 1024 + tid;
        int row = flat >> 5, ch = flat & 31;
        ushort4 bv;
        bv.x = f2bf(hq[r].x); bv.y = f2bf(hq[r].y);
        bv.z = f2bf(hq[r].z); bv.w = f2bf(hq[r].w);
        *(ushort4*)(HBF + swz1k((unsigned)row * 1024u + (unsigned)(q * 32 + ch) * 8u)) = bv;
    }
}

// GEMM over kc = kcbase..kcbase+3, 2-deep rolling Pc prefetch.
// Wave slice: (rw = row-half 0..1, cw = col-octant 0..7): acc[2][4] covers
// rows rw*32..+31 x cols cw*64..+63. Only 2 a-frag LDS reads per kc per wave
// (halves the per-block LDS read pressure vs the 4-read variant); Pc j-slices
// read 2x redundantly across the row-halves (L2-cheap).
template<bool PREF>
__device__ __forceinline__ void gemm_q(
    int kcbase, int tid, int rl, int kg, int rw,
    const unsigned short* bptr, char* HBF,
    bf16x8 (&st0)[4], bf16x8 (&st1)[4],
    f32x4 (&acc)[2][4],
    float4 (&hq)[2], const float4* hsrc, int hq_q)
{
    #pragma unroll
    for (int k = 0; k < 4; ++k) {
        const int kc = kcbase + k;
        bf16x8 bn[4];
        if (kc + 2 < 16) {
            #pragma unroll
            for (int jj = 0; jj < 4; ++jj)
                bn[jj] = *(const bf16x8*)(bptr + (kc + 2) * 16384 + jj * 512);
        }
        if (PREF && k == 1) {
            SB();
            issue_q(hq_q, tid, hsrc, hq);
            SB();
        }
        bf16x8 a[2];
        #pragma unroll
        for (int i = 0; i < 2; ++i) {
            unsigned off = (unsigned)(rw * 32 + i * 16 + rl) * 1024u + (unsigned)kc * 64u + (unsigned)kg * 16u;
            a[i] = *(bf16x8*)(HBF + swz1k(off));
        }
        #pragma unroll
        for (int i = 0; i < 2; ++i)
            #pragma unroll
            for (int jj = 0; jj < 4; ++jj)
                acc[i][jj] = __builtin_amdgcn_mfma_f32_16x16x32_bf16(a[i], st0[jj], acc[i][jj], 0, 0, 0);
        #pragma unroll
        for (int jj = 0; jj < 4; ++jj) { st0[jj] = st1[jj]; st1[jj] = bn[jj]; }
    }
}

// ---------------- K2: fused main kernel. 1 block = 4 batches = 64 H rows,
// 1024 threads (16 waves, 4/SIMD). r16 structure; T-GEMM wave slice changed
// to 2 row-halves x 8 col-octants (LDS-read pressure halved).
__global__ __launch_bounds__(1024, 4) void attn_main_kernel(
    const float* __restrict__ H, const float* __restrict__ F,
    const unsigned short* __restrict__ Pc,
    float* __restrict__ out, unsigned short* __restrict__ g_ws)
{
    extern __shared__ char smem[];
    char* HBF  = smem;                        // 64 rows x 1024B, swizzled (64 KB)
    char* TBF  = smem + 65536;                // 64 KB
    float* wbuf = (float*)(smem + 131072);    // [4][16]
    float* FL   = (float*)(smem + 131328);    // [64]
    float* LFL  = (float*)(smem + 131584);    // [64]

    const int tid = threadIdx.x;
    const int wv = tid >> 6;                  // 0..15
    const int ln = tid & 63;
    const int rl = ln & 15;
    const int kg = ln >> 4;
    const int rw = wv >> 3;                   // row half 0..1
    const int cw = wv & 7;                    // col octant 0..7
    const int blk = blockIdx.x;
    const long long gr0 = (long long)blk * 64;
    const float4* hsrc = (const float4*)(H + gr0 * 512);

    float fval = 0.f;
    if (tid < 64) fval = F[blk * 64 + tid];

    float4 hqA[2], hqB[2];
    issue_q(0, tid, hsrc, hqA);

    // per-wave j-slice: j = cw*64 + jj*16 + rl, jj in {0..3}
    const unsigned short* bptr = Pc + ((cw * 64 + rl) * 32 + kg * 8);
    bf16x8 st0[4], st1[4];
    #pragma unroll
    for (int jj = 0; jj < 4; ++jj) st0[jj] = *(const bf16x8*)(bptr + 0 * 16384 + jj * 512);
    #pragma unroll
    for (int jj = 0; jj < 4; ++jj) st1[jj] = *(const bf16x8*)(bptr + 1 * 16384 + jj * 512);

    issue_q(1, tid, hsrc, hqB);

    if (tid < 64) {
        FL[tid] = fval;
        LFL[tid] = logf(fval + 1e-8f);
    }

    f32x4 acc[2][4];
    #pragma unroll
    for (int i = 0; i < 2; ++i)
        #pragma unroll
        for (int jj = 0; jj < 4; ++jj)
            acc[i][jj] = f32x4{0.f, 0.f, 0.f, 0.f};

    convert_q(0, tid, HBF, hqA);
    bar_lgkm();
    gemm_q<true >(0,  tid, rl, kg, rw, bptr, HBF, st0, st1, acc, hqA, hsrc, 2);
    convert_q(1, tid, HBF, hqB);
    bar_lgkm();
    gemm_q<true >(4,  tid, rl, kg, rw, bptr, HBF, st0, st1, acc, hqB, hsrc, 3);
    convert_q(2, tid, HBF, hqA);
    bar_lgkm();
    gemm_q<false>(8,  tid, rl, kg, rw, bptr, HBF, st0, st1, acc, hqA, hsrc, 0);
    convert_q(3, tid, HBF, hqB);
    bar_lgkm();
    gemm_q<false>(12, tid, rl, kg, rw, bptr, HBF, st0, st1, acc, hqB, hsrc, 0);

    // write T into TBF (C layout: col=lane&15, row=(lane>>4)*4+p)
    #pragma unroll
    for (int i = 0; i < 2; ++i)
        #pragma unroll
        for (int jj = 0; jj < 4; ++jj)
            #pragma unroll
            for (int p = 0; p < 4; ++p) {
                unsigned row = (unsigned)(rw * 32 + i * 16 + kg * 4 + p);
                unsigned col = (unsigned)(cw * 64 + jj * 16 + rl);
                *(unsigned short*)(TBF + swz1k(row * 1024u + col * 2u)) = f2bf(acc[i][jj][p]);
            }
    bar_lgkm();   // TBF ready

    // ---- phase 3: waves 0-3: scores+softmax+w ; waves 4-11: residual pool
    if (wv < 4) {
        f32x4 sc0 = f32x4{0.f,0.f,0.f,0.f}, sc1 = sc0, sc2 = sc0, sc3 = sc0;
        __builtin_amdgcn_s_setprio(1);
        #pragma unroll
        for (int kc = 0; kc < 16; ++kc) {
            unsigned off = (unsigned)(wv * 16 + rl) * 1024u + (unsigned)kc * 64u + (unsigned)kg * 16u;
            bf16x8 aT = *(bf16x8*)(TBF + swz1k(off));
            bf16x8 bH = *(bf16x8*)(HBF + swz1k(off));   // H rows as B == H^T
            if ((kc & 3) == 0) sc0 = __builtin_amdgcn_mfma_f32_16x16x32_bf16(aT, bH, sc0, 0, 0, 0);
            else if ((kc & 3) == 1) sc1 = __builtin_amdgcn_mfma_f32_16x16x32_bf16(aT, bH, sc1, 0, 0, 0);
            else if ((kc & 3) == 2) sc2 = __builtin_amdgcn_mfma_f32_16x16x32_bf16(aT, bH, sc2, 0, 0, 0);
            else sc3 = __builtin_amdgcn_mfma_f32_16x16x32_bf16(aT, bH, sc3, 0, 0, 0);
        }
        __builtin_amdgcn_s_setprio(0);
        f32x4 sc;
        #pragma unroll
        for (int p = 0; p < 4; ++p) sc[p] = (sc0[p] + sc1[p]) + (sc2[p] + sc3[p]);

        float bias = LFL[wv * 16 + rl];
        float alpha[4];
        #pragma unroll
        for (int p = 0; p < 4; ++p) {
            float s = sc[p] * 0.044194173824159216f + bias;  // 1/sqrt(512)
            float m = s;
            m = fmaxf(m, __shfl_xor(m, 8));
            m = fmaxf(m, __shfl_xor(m, 4));
            m = fmaxf(m, __shfl_xor(m, 2));
            m = fmaxf(m, __shfl_xor(m, 1));
            float e = expf(s - m);
            float sum = e;
            sum += __shfl_xor(sum, 8);
            sum += __shfl_xor(sum, 4);
            sum += __shfl_xor(sum, 2);
            sum += __shfl_xor(sum, 1);
            alpha[p] = e / sum;
        }
        float part = 0.f;
        #pragma unroll
        for (int p = 0; p < 4; ++p) part += FL[wv * 16 + kg * 4 + p] * alpha[p];
        part += __shfl_xor(part, 16);
        part += __shfl_xor(part, 32);
        if (ln < 16) wbuf[wv * 16 + ln] = part;
    } else if (wv < 12) {
        // residual F-pool: unit = (batch bb, d-half dh); lane covers 4 d
        int u = wv - 4;
        int bb = u >> 1, dh = u & 1;
        const long long Bg = (long long)blk * 4 + bb;
        int d0 = dh * 256 + ln * 4;
        float o[4];
        #pragma unroll
        for (int q = 0; q < 4; ++q) o[q] = 0.f;
        #pragma unroll
        for (int k = 0; k < 16; ++k) {
            unsigned off = (unsigned)(bb * 16 + k) * 1024u + (unsigned)d0 * 2u;
            ushort4 h = *(ushort4*)(HBF + swz1k(off));
            float fk = FL[bb * 16 + k];
            o[0] = fmaf(fk, bf2f(h.x), o[0]); o[1] = fmaf(fk, bf2f(h.y), o[1]);
            o[2] = fmaf(fk, bf2f(h.z), o[2]); o[3] = fmaf(fk, bf2f(h.w), o[3]);
        }
        float4 oa; oa.x = o[0]; oa.y = o[1]; oa.z = o[2]; oa.w = o[3];
        *(float4*)(out + Bg * 512 + d0) = oa;
    }
    bar_lgkm();   // wbuf ready

    // ---- phase 4: g (bf16). 16 waves = 4 batches x 4 d-quarters, from LDS.
    {
        int bb = wv >> 2, q4 = wv & 3;
        const long long Bg = (long long)blk * 4 + bb;
        int d0 = q4 * 128 + ln * 2;
        float g0 = 0.f, g1 = 0.f;
        #pragma unroll
        for (int k = 0; k < 16; ++k) {
            unsigned off = (unsigned)(bb * 16 + k) * 1024u + (unsigned)d0 * 2u;
            ushort2 h = *(ushort2*)(HBF + swz1k(off));
            float wk = wbuf[bb * 16 + k];
            g0 = fmaf(wk, bf2f(h.x), g0); g1 = fmaf(wk, bf2f(h.y), g1);
        }
        ushort2 g2; g2.x = f2bf(g0); g2.y = f2bf(g1);
        *(ushort2*)(g_ws + Bg * 512 + d0) = g2;
    }
}

// ---------------- K3: out += g @ Wv^T   (8192x512 @ 512x512, bf16 MFMA)
// 512 blocks x 16-row tiles (16 KB LDS -> 2 blocks/CU for overlap).
__global__ __launch_bounds__(256) void out_gemm_kernel(
    const unsigned short* __restrict__ g_ws,
    const unsigned short* __restrict__ Wvb,
    float* __restrict__ out)
{
    extern __shared__ char smem[];  // 16 KB: 16 rows x 1024B, swizzled
    const int tid = threadIdx.x;
    const int wv = tid >> 6, ln = tid & 63;
    const int rl = ln & 15, kg = ln >> 4;
    const long long r0 = (long long)blockIdx.x * 16;
    {
        const uint4* src = (const uint4*)(g_ws + r0 * 512);
        #pragma unroll
        for (int q = 0; q < 4; ++q) {
            int idx = q * 256 + tid;       // [0,1024) uint4 = 16 KB
            *(uint4*)(smem + swz1k((unsigned)idx * 16u)) = src[idx];
        }
    }
    __syncthreads();
    f32x4 acc[8];
    #pragma unroll
    for (int jj = 0; jj < 8; ++jj)
        acc[jj] = f32x4{0.f, 0.f, 0.f, 0.f};
    for (int kc = 0; kc < 16; ++kc) {
        bf16x8 a;
        {
            unsigned off = (unsigned)rl * 1024u + (unsigned)kc * 64u + (unsigned)kg * 16u;
            a = *(bf16x8*)(smem + swz1k(off));
        }
        bf16x8 bfr[8];
        #pragma unroll
        for (int jj = 0; jj < 8; ++jj) {
            int n = wv * 128 + jj * 16 + rl;
            bfr[jj] = *(const bf16x8*)(Wvb + n * 512 + kc * 32 + kg * 8);
        }
        #pragma unroll
        for (int jj = 0; jj < 8; ++jj)
            acc[jj] = __builtin_amdgcn_mfma_f32_16x16x32_bf16(a, bfr[jj], acc[jj], 0, 0, 0);
    }
    #pragma unroll
    for (int jj = 0; jj < 8; ++jj)
        #pragma unroll
        for (int p = 0; p < 4; ++p) {
            int row = kg * 4 + p;
            int col = wv * 128 + jj * 16 + rl;
            out[(r0 + row) * 512 + col] += acc[jj][p];
        }
}

extern "C" void kernel_launch(void* const* d_in, const int* in_sizes, int n_in,
                              void* d_out, int out_size, void* d_ws, size_t ws_size,
                              hipStream_t stream)
{
    const float* H  = (const float*)d_in[0];
    const float* F  = (const float*)d_in[1];
    const float* Wq = (const float*)d_in[2];
    const float* Wk = (const float*)d_in[3];
    const float* Wv = (const float*)d_in[4];
    float* out = (float*)d_out;

    unsigned short* Pc  = (unsigned short*)d_ws;       // 16*512*32   = 262144 bf16
    unsigned short* Wvb = Pc + 262144;                 // 512*512     = 262144 bf16
    unsigned short* g   = Wvb + 262144;                // 8192*512    = 4194304 bf16
    (void)in_sizes; (void)n_in; (void)out_size; (void)ws_size;

    prep_kernel<<<dim3(2048), dim3(256), 0, stream>>>(Wq, Wk, Wv, Pc, Wvb);
    attn_main_kernel<<<dim3(2048), dim3(1024), 131840, stream>>>(H, F, Pc, out, g);
    out_gemm_kernel<<<dim3(512), dim3(256), 16384, stream>>>(g, Wvb, out);
}

// Round 18
// 196.521 us; speedup vs baseline: 1.2633x; 1.2633x over previous
//
#include <hip/hip_runtime.h>

typedef __bf16 bf16x8 __attribute__((ext_vector_type(8)));
typedef float f32x4 __attribute__((ext_vector_type(4)));

__device__ __forceinline__ unsigned short f2bf(float f) {
    unsigned int u = __builtin_bit_cast(unsigned int, f);
    u += 0x7fffu + ((u >> 16) & 1u);
    return (unsigned short)(u >> 16);
}
__device__ __forceinline__ float bf2f(unsigned short u) {
    return __builtin_bit_cast(float, (unsigned)u << 16);
}

// XOR swizzle for 1024B-row LDS tiles: byte ^= ((row&7)<<4)
__device__ __forceinline__ unsigned swz1k(unsigned byte) {
    return byte ^ ((byte >> 6) & 0x70u);
}

// Raw barrier: LDS-visibility only; does NOT drain vmcnt.
__device__ __forceinline__ void bar_lgkm() {
    asm volatile("s_waitcnt lgkmcnt(0)\n\ts_barrier" ::: "memory");
}
#define SB() __builtin_amdgcn_sched_barrier(0)

// ---------------- K1: Pc[kc][j][t] = M[kc*32+t][j], M = Wq^T Wk  (bf16)
// plus Wv -> bf16 copy.
__global__ __launch_bounds__(256) void prep_kernel(
    const float* __restrict__ Wq, const float* __restrict__ Wk,
    const float* __restrict__ Wv, unsigned short* __restrict__ Pc,
    unsigned short* __restrict__ Wvb)
{
    int b = blockIdx.x;
    if (b < 1024) {
        int j0 = (b >> 4) * 8;
        int kc = b & 15;
        int jloc = threadIdx.x >> 5;
        int t = threadIdx.x & 31;
        int j = j0 + jloc, d = kc * 32 + t;
        float acc = 0.f;
        #pragma unroll 8
        for (int e = 0; e < 512; ++e)
            acc = fmaf(Wk[e * 512 + j], Wq[e * 512 + d], acc);
        Pc[((kc * 512) + j) * 32 + t] = f2bf(acc);
    } else {
        int i = (b - 1024) * 256 + (int)threadIdx.x;
        Wvb[i] = f2bf(Wv[i]);
    }
}

// issue H column-quarter q (64-row tile, 1024 threads): 2 float4/thread.
__device__ __forceinline__ void issue_q(int q, int tid, const float4* hsrc, float4 (&hq)[2]) {
    #pragma unroll
    for (int r = 0; r < 2; ++r) {
        int flat = r * 1024 + tid;         // [0,2048)
        hq[r] = hsrc[(flat >> 5) * 128 + q * 32 + (flat & 31)];
    }
}

// convert quarter q -> bf16 swizzled HBF (consumes hq)
__device__ __forceinline__ void convert_q(int q, int tid, char* HBF, float4 (&hq)[2]) {
    #pragma unroll
    for (int r = 0; r < 2; ++r) {
        int flat = r * 1024 + tid;
        int row = flat >> 5, ch = flat & 31;
        ushort4 bv;
        bv.x = f2bf(hq[r].x); bv.y = f2bf(hq[r].y);
        bv.z = f2bf(hq[r].z); bv.w = f2bf(hq[r].w);
        *(ushort4*)(HBF + swz1k((unsigned)row * 1024u + (unsigned)(q * 32 + ch) * 8u)) = bv;
    }
}

// GEMM over kc = kcbase..kcbase+3, 2-deep rolling Pc prefetch, per-wave
// j-slice of 32 cols (2 frags). If PREF: issue H quarter at k==1 AFTER that
// iter's Pc issue.
template<bool PREF>
__device__ __forceinline__ void gemm_q(
    int kcbase, int tid, int rl, int kg,
    const unsigned short* bptr, char* HBF,
    bf16x8 (&st0)[2], bf16x8 (&st1)[2],
    f32x4 (&acc)[4][2],
    float4 (&hq)[2], const float4* hsrc, int hq_q)
{
    #pragma unroll
    for (int k = 0; k < 4; ++k) {
        const int kc = kcbase + k;
        bf16x8 bn[2];
        if (kc + 2 < 16) {
            #pragma unroll
            for (int jj = 0; jj < 2; ++jj)
                bn[jj] = *(const bf16x8*)(bptr + (kc + 2) * 16384 + jj * 512);
        }
        if (PREF && k == 1) {
            SB();
            issue_q(hq_q, tid, hsrc, hq);
            SB();
        }
        bf16x8 a[4];
        #pragma unroll
        for (int i = 0; i < 4; ++i) {
            unsigned off = (unsigned)(i * 16 + rl) * 1024u + (unsigned)kc * 64u + (unsigned)kg * 16u;
            a[i] = *(bf16x8*)(HBF + swz1k(off));
        }
        #pragma unroll
        for (int i = 0; i < 4; ++i)
            #pragma unroll
            for (int jj = 0; jj < 2; ++jj)
                acc[i][jj] = __builtin_amdgcn_mfma_f32_16x16x32_bf16(a[i], st0[jj], acc[i][jj], 0, 0, 0);
        #pragma unroll
        for (int jj = 0; jj < 2; ++jj) { st0[jj] = st1[jj]; st1[jj] = bn[jj]; }
    }
}

// ---------------- K2: fused main kernel (r11 structure, empirical best).
// 1 block = 4 batches = 64 H rows, 1024 threads (16 waves, 4/SIMD).
__global__ __launch_bounds__(1024, 4) void attn_main_kernel(
    const float* __restrict__ H, const float* __restrict__ F,
    const unsigned short* __restrict__ Pc,
    float* __restrict__ out, unsigned short* __restrict__ g_ws)
{
    extern __shared__ char smem[];
    char* HBF  = smem;                        // 64 rows x 1024B, swizzled (64 KB)
    char* TBF  = smem + 65536;                // 64 KB
    float* wbuf = (float*)(smem + 131072);    // [4][16]
    float* FL   = (float*)(smem + 131328);    // [64]
    float* LFL  = (float*)(smem + 131584);    // [64]

    const int tid = threadIdx.x;
    const int wv = tid >> 6;                  // 0..15
    const int ln = tid & 63;
    const int rl = ln & 15;
    const int kg = ln >> 4;
    const int blk = blockIdx.x;
    const long long gr0 = (long long)blk * 64;
    const float4* hsrc = (const float4*)(H + gr0 * 512);

    float fval = 0.f;
    if (tid < 64) fval = F[blk * 64 + tid];

    float4 hqA[2], hqB[2];
    issue_q(0, tid, hsrc, hqA);

    // per-wave j-slice: j = wv*32 + jj*16 + rl, jj in {0,1}
    const unsigned short* bptr = Pc + ((wv * 32 + rl) * 32 + kg * 8);
    bf16x8 st0[2], st1[2];
    #pragma unroll
    for (int jj = 0; jj < 2; ++jj) st0[jj] = *(const bf16x8*)(bptr + 0 * 16384 + jj * 512);
    #pragma unroll
    for (int jj = 0; jj < 2; ++jj) st1[jj] = *(const bf16x8*)(bptr + 1 * 16384 + jj * 512);

    issue_q(1, tid, hsrc, hqB);

    if (tid < 64) {
        FL[tid] = fval;
        LFL[tid] = logf(fval + 1e-8f);
    }

    f32x4 acc[4][2];
    #pragma unroll
    for (int i = 0; i < 4; ++i)
        #pragma unroll
        for (int jj = 0; jj < 2; ++jj)
            acc[i][jj] = f32x4{0.f, 0.f, 0.f, 0.f};

    convert_q(0, tid, HBF, hqA);
    bar_lgkm();
    gemm_q<true >(0,  tid, rl, kg, bptr, HBF, st0, st1, acc, hqA, hsrc, 2);
    convert_q(1, tid, HBF, hqB);
    bar_lgkm();
    gemm_q<true >(4,  tid, rl, kg, bptr, HBF, st0, st1, acc, hqB, hsrc, 3);
    convert_q(2, tid, HBF, hqA);
    bar_lgkm();
    gemm_q<false>(8,  tid, rl, kg, bptr, HBF, st0, st1, acc, hqA, hsrc, 0);
    convert_q(3, tid, HBF, hqB);
    bar_lgkm();
    gemm_q<false>(12, tid, rl, kg, bptr, HBF, st0, st1, acc, hqB, hsrc, 0);

    // write T into TBF (C layout: col=lane&15, row=(lane>>4)*4+p)
    #pragma unroll
    for (int i = 0; i < 4; ++i)
        #pragma unroll
        for (int jj = 0; jj < 2; ++jj)
            #pragma unroll
            for (int p = 0; p < 4; ++p) {
                unsigned row = (unsigned)(i * 16 + kg * 4 + p);
                unsigned col = (unsigned)(wv * 32 + jj * 16 + rl);
                *(unsigned short*)(TBF + swz1k(row * 1024u + col * 2u)) = f2bf(acc[i][jj][p]);
            }
    bar_lgkm();   // TBF ready

    // ---- phase 3: waves 0-3: scores+softmax+w ; waves 4-11: residual pool
    if (wv < 4) {
        f32x4 sc0 = f32x4{0.f,0.f,0.f,0.f}, sc1 = sc0, sc2 = sc0, sc3 = sc0;
        __builtin_amdgcn_s_setprio(1);
        #pragma unroll
        for (int kc = 0; kc < 16; ++kc) {
            unsigned off = (unsigned)(wv * 16 + rl) * 1024u + (unsigned)kc * 64u + (unsigned)kg * 16u;
            bf16x8 aT = *(bf16x8*)(TBF + swz1k(off));
            bf16x8 bH = *(bf16x8*)(HBF + swz1k(off));   // H rows as B == H^T
            if ((kc & 3) == 0) sc0 = __builtin_amdgcn_mfma_f32_16x16x32_bf16(aT, bH, sc0, 0, 0, 0);
            else if ((kc & 3) == 1) sc1 = __builtin_amdgcn_mfma_f32_16x16x32_bf16(aT, bH, sc1, 0, 0, 0);
            else if ((kc & 3) == 2) sc2 = __builtin_amdgcn_mfma_f32_16x16x32_bf16(aT, bH, sc2, 0, 0, 0);
            else sc3 = __builtin_amdgcn_mfma_f32_16x16x32_bf16(aT, bH, sc3, 0, 0, 0);
        }
        __builtin_amdgcn_s_setprio(0);
        f32x4 sc;
        #pragma unroll
        for (int p = 0; p < 4; ++p) sc[p] = (sc0[p] + sc1[p]) + (sc2[p] + sc3[p]);

        float bias = LFL[wv * 16 + rl];
        float alpha[4];
        #pragma unroll
        for (int p = 0; p < 4; ++p) {
            float s = sc[p] * 0.044194173824159216f + bias;  // 1/sqrt(512)
            float m = s;
            m = fmaxf(m, __shfl_xor(m, 8));
            m = fmaxf(m, __shfl_xor(m, 4));
            m = fmaxf(m, __shfl_xor(m, 2));
            m = fmaxf(m, __shfl_xor(m, 1));
            float e = expf(s - m);
            float sum = e;
            sum += __shfl_xor(sum, 8);
            sum += __shfl_xor(sum, 4);
            sum += __shfl_xor(sum, 2);
            sum += __shfl_xor(sum, 1);
            alpha[p] = e / sum;
        }
        float part = 0.f;
        #pragma unroll
        for (int p = 0; p < 4; ++p) part += FL[wv * 16 + kg * 4 + p] * alpha[p];
        part += __shfl_xor(part, 16);
        part += __shfl_xor(part, 32);
        if (ln < 16) wbuf[wv * 16 + ln] = part;
    } else if (wv < 12) {
        // residual F-pool: unit = (batch bb, d-half dh); lane covers 4 d
        int u = wv - 4;
        int bb = u >> 1, dh = u & 1;
        const long long Bg = (long long)blk * 4 + bb;
        int d0 = dh * 256 + ln * 4;
        float o[4];
        #pragma unroll
        for (int q = 0; q < 4; ++q) o[q] = 0.f;
        #pragma unroll
        for (int k = 0; k < 16; ++k) {
            unsigned off = (unsigned)(bb * 16 + k) * 1024u + (unsigned)d0 * 2u;
            ushort4 h = *(ushort4*)(HBF + swz1k(off));
            float fk = FL[bb * 16 + k];
            o[0] = fmaf(fk, bf2f(h.x), o[0]); o[1] = fmaf(fk, bf2f(h.y), o[1]);
            o[2] = fmaf(fk, bf2f(h.z), o[2]); o[3] = fmaf(fk, bf2f(h.w), o[3]);
        }
        float4 oa; oa.x = o[0]; oa.y = o[1]; oa.z = o[2]; oa.w = o[3];
        *(float4*)(out + Bg * 512 + d0) = oa;
    }
    bar_lgkm();   // wbuf ready

    // ---- phase 4: g (bf16). 16 waves = 4 batches x 4 d-quarters, from LDS.
    {
        int bb = wv >> 2, q4 = wv & 3;
        const long long Bg = (long long)blk * 4 + bb;
        int d0 = q4 * 128 + ln * 2;
        float g0 = 0.f, g1 = 0.f;
        #pragma unroll
        for (int k = 0; k < 16; ++k) {
            unsigned off = (unsigned)(bb * 16 + k) * 1024u + (unsigned)d0 * 2u;
            ushort2 h = *(ushort2*)(HBF + swz1k(off));
            float wk = wbuf[bb * 16 + k];
            g0 = fmaf(wk, bf2f(h.x), g0); g1 = fmaf(wk, bf2f(h.y), g1);
        }
        ushort2 g2; g2.x = f2bf(g0); g2.y = f2bf(g1);
        *(ushort2*)(g_ws + Bg * 512 + d0) = g2;
    }
}

// ---------------- K3: out += g @ Wv^T   (8192x512 @ 512x512, bf16 MFMA)
// r11 configuration: 256 blocks x 32-row tiles, 32 KB LDS.
__global__ __launch_bounds__(256) void out_gemm_kernel(
    const unsigned short* __restrict__ g_ws,
    const unsigned short* __restrict__ Wvb,
    float* __restrict__ out)
{
    extern __shared__ char smem[];  // 32 KB: 32 rows x 1024B, swizzled
    const int tid = threadIdx.x;
    const int wv = tid >> 6, ln = tid & 63;
    const int rl = ln & 15, kg = ln >> 4;
    const long long r0 = (long long)blockIdx.x * 32;
    {
        const uint4* src = (const uint4*)(g_ws + r0 * 512);
        #pragma unroll
        for (int q = 0; q < 8; ++q) {
            int idx = q * 256 + tid;
            *(uint4*)(smem + swz1k((unsigned)idx * 16u)) = src[idx];
        }
    }
    __syncthreads();
    f32x4 acc[2][8];
    #pragma unroll
    for (int i = 0; i < 2; ++i)
        #pragma unroll
        for (int jj = 0; jj < 8; ++jj)
            acc[i][jj] = f32x4{0.f, 0.f, 0.f, 0.f};
    for (int kc = 0; kc < 16; ++kc) {
        bf16x8 a[2];
        #pragma unroll
        for (int i = 0; i < 2; ++i) {
            unsigned off = (unsigned)(i * 16 + rl) * 1024u + (unsigned)kc * 64u + (unsigned)kg * 16u;
            a[i] = *(bf16x8*)(smem + swz1k(off));
        }
        bf16x8 bfr[8];
        #pragma unroll
        for (int jj = 0; jj < 8; ++jj) {
            int n = wv * 128 + jj * 16 + rl;
            bfr[jj] = *(const bf16x8*)(Wvb + n * 512 + kc * 32 + kg * 8);
        }
        #pragma unroll
        for (int i = 0; i < 2; ++i)
            #pragma unroll
            for (int jj = 0; jj < 8; ++jj)
                acc[i][jj] = __builtin_amdgcn_mfma_f32_16x16x32_bf16(a[i], bfr[jj], acc[i][jj], 0, 0, 0);
    }
    #pragma unroll
    for (int i = 0; i < 2; ++i)
        #pragma unroll
        for (int jj = 0; jj < 8; ++jj)
            #pragma unroll
            for (int p = 0; p < 4; ++p) {
                int row = i * 16 + kg * 4 + p;
                int col = wv * 128 + jj * 16 + rl;
                out[(r0 + row) * 512 + col] += acc[i][jj][p];
            }
}

extern "C" void kernel_launch(void* const* d_in, const int* in_sizes, int n_in,
                              void* d_out, int out_size, void* d_ws, size_t ws_size,
                              hipStream_t stream)
{
    const float* H  = (const float*)d_in[0];
    const float* F  = (const float*)d_in[1];
    const float* Wq = (const float*)d_in[2];
    const float* Wk = (const float*)d_in[3];
    const float* Wv = (const float*)d_in[4];
    float* out = (float*)d_out;

    unsigned short* Pc  = (unsigned short*)d_ws;       // 16*512*32   = 262144 bf16
    unsigned short* Wvb = Pc + 262144;                 // 512*512     = 262144 bf16
    unsigned short* g   = Wvb + 262144;                // 8192*512    = 4194304 bf16
    (void)in_sizes; (void)n_in; (void)out_size; (void)ws_size;

    prep_kernel<<<dim3(2048), dim3(256), 0, stream>>>(Wq, Wk, Wv, Pc, Wvb);
    attn_main_kernel<<<dim3(2048), dim3(1024), 131840, stream>>>(H, F, Pc, out, g);
    out_gemm_kernel<<<dim3(256), dim3(256), 32768, stream>>>(g, Wvb, out);
}

// Round 19
// 193.606 us; speedup vs baseline: 1.2823x; 1.0151x over previous
//
#include <hip/hip_runtime.h>

typedef __bf16 bf16x8 __attribute__((ext_vector_type(8)));
typedef float f32x4 __attribute__((ext_vector_type(4)));

__device__ __forceinline__ unsigned short f2bf(float f) {
    unsigned int u = __builtin_bit_cast(unsigned int, f);
    u += 0x7fffu + ((u >> 16) & 1u);
    return (unsigned short)(u >> 16);
}
__device__ __forceinline__ float bf2f(unsigned short u) {
    return __builtin_bit_cast(float, (unsigned)u << 16);
}

// XOR swizzle for 1024B-row LDS tiles: byte ^= ((row&7)<<4)
__device__ __forceinline__ unsigned swz1k(unsigned byte) {
    return byte ^ ((byte >> 6) & 0x70u);
}

// Raw barrier: LDS-visibility only; does NOT drain vmcnt.
__device__ __forceinline__ void bar_lgkm() {
    asm volatile("s_waitcnt lgkmcnt(0)\n\ts_barrier" ::: "memory");
}
#define SB() __builtin_amdgcn_sched_barrier(0)

// ---------------- K1: Pc[kc][j][t] = M[kc*32+t][j], M = Wq^T Wk  (bf16)
// plus Wv -> bf16 copy.
__global__ __launch_bounds__(256) void prep_kernel(
    const float* __restrict__ Wq, const float* __restrict__ Wk,
    const float* __restrict__ Wv, unsigned short* __restrict__ Pc,
    unsigned short* __restrict__ Wvb)
{
    int b = blockIdx.x;
    if (b < 1024) {
        int j0 = (b >> 4) * 8;
        int kc = b & 15;
        int jloc = threadIdx.x >> 5;
        int t = threadIdx.x & 31;
        int j = j0 + jloc, d = kc * 32 + t;
        float acc = 0.f;
        #pragma unroll 8
        for (int e = 0; e < 512; ++e)
            acc = fmaf(Wk[e * 512 + j], Wq[e * 512 + d], acc);
        Pc[((kc * 512) + j) * 32 + t] = f2bf(acc);
    } else {
        int i = (b - 1024) * 256 + (int)threadIdx.x;
        Wvb[i] = f2bf(Wv[i]);
    }
}

// issue H column-quarter q (64-row tile, 1024 threads): 2 float4/thread.
__device__ __forceinline__ void issue_q(int q, int tid, const float4* hsrc, float4 (&hq)[2]) {
    #pragma unroll
    for (int r = 0; r < 2; ++r) {
        int flat = r * 1024 + tid;         // [0,2048)
        hq[r] = hsrc[(flat >> 5) * 128 + q * 32 + (flat & 31)];
    }
}

// convert quarter q -> bf16 swizzled HBF (consumes hq)
__device__ __forceinline__ void convert_q(int q, int tid, char* HBF, float4 (&hq)[2]) {
    #pragma unroll
    for (int r = 0; r < 2; ++r) {
        int flat = r * 1024 + tid;
        int row = flat >> 5, ch = flat & 31;
        ushort4 bv;
        bv.x = f2bf(hq[r].x); bv.y = f2bf(hq[r].y);
        bv.z = f2bf(hq[r].z); bv.w = f2bf(hq[r].w);
        *(ushort4*)(HBF + swz1k((unsigned)row * 1024u + (unsigned)(q * 32 + ch) * 8u)) = bv;
    }
}

// GEMM over kc = kcbase..kcbase+3, 2-deep rolling Pc prefetch, per-wave
// j-slice of 32 cols (2 frags). If PREF: issue H quarter at k==1 AFTER that
// iter's Pc issue.
template<bool PREF>
__device__ __forceinline__ void gemm_q(
    int kcbase, int tid, int rl, int kg,
    const unsigned short* bptr, char* HBF,
    bf16x8 (&st0)[2], bf16x8 (&st1)[2],
    f32x4 (&acc)[4][2],
    float4 (&hq)[2], const float4* hsrc, int hq_q)
{
    #pragma unroll
    for (int k = 0; k < 4; ++k) {
        const int kc = kcbase + k;
        bf16x8 bn[2];
        if (kc + 2 < 16) {
            #pragma unroll
            for (int jj = 0; jj < 2; ++jj)
                bn[jj] = *(const bf16x8*)(bptr + (kc + 2) * 16384 + jj * 512);
        }
        if (PREF && k == 1) {
            SB();
            issue_q(hq_q, tid, hsrc, hq);
            SB();
        }
        bf16x8 a[4];
        #pragma unroll
        for (int i = 0; i < 4; ++i) {
            unsigned off = (unsigned)(i * 16 + rl) * 1024u + (unsigned)kc * 64u + (unsigned)kg * 16u;
            a[i] = *(bf16x8*)(HBF + swz1k(off));
        }
        #pragma unroll
        for (int i = 0; i < 4; ++i)
            #pragma unroll
            for (int jj = 0; jj < 2; ++jj)
                acc[i][jj] = __builtin_amdgcn_mfma_f32_16x16x32_bf16(a[i], st0[jj], acc[i][jj], 0, 0, 0);
        #pragma unroll
        for (int jj = 0; jj < 2; ++jj) { st0[jj] = st1[jj]; st1[jj] = bn[jj]; }
    }
}

// ---------------- K2: fused main kernel (r11 structure, empirical best).
// 1 block = 4 batches = 64 H rows, 1024 threads (16 waves, 4/SIMD).
__global__ __launch_bounds__(1024, 4) void attn_main_kernel(
    const float* __restrict__ H, const float* __restrict__ F,
    const unsigned short* __restrict__ Pc,
    float* __restrict__ out, unsigned short* __restrict__ g_ws)
{
    extern __shared__ char smem[];
    char* HBF  = smem;                        // 64 rows x 1024B, swizzled (64 KB)
    char* TBF  = smem + 65536;                // 64 KB
    float* wbuf = (float*)(smem + 131072);    // [4][16]
    float* FL   = (float*)(smem + 131328);    // [64]
    float* LFL  = (float*)(smem + 131584);    // [64]

    const int tid = threadIdx.x;
    const int wv = tid >> 6;                  // 0..15
    const int ln = tid & 63;
    const int rl = ln & 15;
    const int kg = ln >> 4;
    const int blk = blockIdx.x;
    const long long gr0 = (long long)blk * 64;
    const float4* hsrc = (const float4*)(H + gr0 * 512);

    float fval = 0.f;
    if (tid < 64) fval = F[blk * 64 + tid];

    float4 hqA[2], hqB[2];
    issue_q(0, tid, hsrc, hqA);

    // per-wave j-slice: j = wv*32 + jj*16 + rl, jj in {0,1}
    const unsigned short* bptr = Pc + ((wv * 32 + rl) * 32 + kg * 8);
    bf16x8 st0[2], st1[2];
    #pragma unroll
    for (int jj = 0; jj < 2; ++jj) st0[jj] = *(const bf16x8*)(bptr + 0 * 16384 + jj * 512);
    #pragma unroll
    for (int jj = 0; jj < 2; ++jj) st1[jj] = *(const bf16x8*)(bptr + 1 * 16384 + jj * 512);

    issue_q(1, tid, hsrc, hqB);

    if (tid < 64) {
        FL[tid] = fval;
        LFL[tid] = logf(fval + 1e-8f);
    }

    f32x4 acc[4][2];
    #pragma unroll
    for (int i = 0; i < 4; ++i)
        #pragma unroll
        for (int jj = 0; jj < 2; ++jj)
            acc[i][jj] = f32x4{0.f, 0.f, 0.f, 0.f};

    convert_q(0, tid, HBF, hqA);
    bar_lgkm();
    gemm_q<true >(0,  tid, rl, kg, bptr, HBF, st0, st1, acc, hqA, hsrc, 2);
    convert_q(1, tid, HBF, hqB);
    bar_lgkm();
    gemm_q<true >(4,  tid, rl, kg, bptr, HBF, st0, st1, acc, hqB, hsrc, 3);
    convert_q(2, tid, HBF, hqA);
    bar_lgkm();
    gemm_q<false>(8,  tid, rl, kg, bptr, HBF, st0, st1, acc, hqA, hsrc, 0);
    convert_q(3, tid, HBF, hqB);
    bar_lgkm();
    gemm_q<false>(12, tid, rl, kg, bptr, HBF, st0, st1, acc, hqB, hsrc, 0);

    // write T into TBF (C layout: col=lane&15, row=(lane>>4)*4+p)
    #pragma unroll
    for (int i = 0; i < 4; ++i)
        #pragma unroll
        for (int jj = 0; jj < 2; ++jj)
            #pragma unroll
            for (int p = 0; p < 4; ++p) {
                unsigned row = (unsigned)(i * 16 + kg * 4 + p);
                unsigned col = (unsigned)(wv * 32 + jj * 16 + rl);
                *(unsigned short*)(TBF + swz1k(row * 1024u + col * 2u)) = f2bf(acc[i][jj][p]);
            }
    bar_lgkm();   // TBF ready

    // ---- phase 3: waves 0-3: scores+softmax+w ; waves 4-11: residual pool
    if (wv < 4) {
        f32x4 sc0 = f32x4{0.f,0.f,0.f,0.f}, sc1 = sc0, sc2 = sc0, sc3 = sc0;
        __builtin_amdgcn_s_setprio(1);
        #pragma unroll
        for (int kc = 0; kc < 16; ++kc) {
            unsigned off = (unsigned)(wv * 16 + rl) * 1024u + (unsigned)kc * 64u + (unsigned)kg * 16u;
            bf16x8 aT = *(bf16x8*)(TBF + swz1k(off));
            bf16x8 bH = *(bf16x8*)(HBF + swz1k(off));   // H rows as B == H^T
            if ((kc & 3) == 0) sc0 = __builtin_amdgcn_mfma_f32_16x16x32_bf16(aT, bH, sc0, 0, 0, 0);
            else if ((kc & 3) == 1) sc1 = __builtin_amdgcn_mfma_f32_16x16x32_bf16(aT, bH, sc1, 0, 0, 0);
            else if ((kc & 3) == 2) sc2 = __builtin_amdgcn_mfma_f32_16x16x32_bf16(aT, bH, sc2, 0, 0, 0);
            else sc3 = __builtin_amdgcn_mfma_f32_16x16x32_bf16(aT, bH, sc3, 0, 0, 0);
        }
        __builtin_amdgcn_s_setprio(0);
        f32x4 sc;
        #pragma unroll
        for (int p = 0; p < 4; ++p) sc[p] = (sc0[p] + sc1[p]) + (sc2[p] + sc3[p]);

        float bias = LFL[wv * 16 + rl];
        float alpha[4];
        #pragma unroll
        for (int p = 0; p < 4; ++p) {
            float s = sc[p] * 0.044194173824159216f + bias;  // 1/sqrt(512)
            float m = s;
            m = fmaxf(m, __shfl_xor(m, 8));
            m = fmaxf(m, __shfl_xor(m, 4));
            m = fmaxf(m, __shfl_xor(m, 2));
            m = fmaxf(m, __shfl_xor(m, 1));
            float e = expf(s - m);
            float sum = e;
            sum += __shfl_xor(sum, 8);
            sum += __shfl_xor(sum, 4);
            sum += __shfl_xor(sum, 2);
            sum += __shfl_xor(sum, 1);
            alpha[p] = e / sum;
        }
        float part = 0.f;
        #pragma unroll
        for (int p = 0; p < 4; ++p) part += FL[wv * 16 + kg * 4 + p] * alpha[p];
        part += __shfl_xor(part, 16);
        part += __shfl_xor(part, 32);
        if (ln < 16) wbuf[wv * 16 + ln] = part;
    } else if (wv < 12) {
        // residual F-pool: unit = (batch bb, d-half dh); lane covers 4 d
        int u = wv - 4;
        int bb = u >> 1, dh = u & 1;
        const long long Bg = (long long)blk * 4 + bb;
        int d0 = dh * 256 + ln * 4;
        float o[4];
        #pragma unroll
        for (int q = 0; q < 4; ++q) o[q] = 0.f;
        #pragma unroll
        for (int k = 0; k < 16; ++k) {
            unsigned off = (unsigned)(bb * 16 + k) * 1024u + (unsigned)d0 * 2u;
            ushort4 h = *(ushort4*)(HBF + swz1k(off));
            float fk = FL[bb * 16 + k];
            o[0] = fmaf(fk, bf2f(h.x), o[0]); o[1] = fmaf(fk, bf2f(h.y), o[1]);
            o[2] = fmaf(fk, bf2f(h.z), o[2]); o[3] = fmaf(fk, bf2f(h.w), o[3]);
        }
        float4 oa; oa.x = o[0]; oa.y = o[1]; oa.z = o[2]; oa.w = o[3];
        *(float4*)(out + Bg * 512 + d0) = oa;
    }
    bar_lgkm();   // wbuf ready

    // ---- phase 4: g (bf16). 16 waves = 4 batches x 4 d-quarters, from LDS.
    {
        int bb = wv >> 2, q4 = wv & 3;
        const long long Bg = (long long)blk * 4 + bb;
        int d0 = q4 * 128 + ln * 2;
        float g0 = 0.f, g1 = 0.f;
        #pragma unroll
        for (int k = 0; k < 16; ++k) {
            unsigned off = (unsigned)(bb * 16 + k) * 1024u + (unsigned)d0 * 2u;
            ushort2 h = *(ushort2*)(HBF + swz1k(off));
            float wk = wbuf[bb * 16 + k];
            g0 = fmaf(wk, bf2f(h.x), g0); g1 = fmaf(wk, bf2f(h.y), g1);
        }
        ushort2 g2; g2.x = f2bf(g0); g2.y = f2bf(g1);
        *(ushort2*)(g_ws + Bg * 512 + d0) = g2;
    }
}

// ---------------- K3: out += g @ Wv^T   (8192x512 @ 512x512, bf16 MFMA)
// 256 blocks x 32-row tiles (same traffic as r11), but 512 threads = 8 waves
// = 2 waves/SIMD for latency hiding (was 1). Wave j-slice 64 cols, acc[2][4].
__global__ __launch_bounds__(512) void out_gemm_kernel(
    const unsigned short* __restrict__ g_ws,
    const unsigned short* __restrict__ Wvb,
    float* __restrict__ out)
{
    extern __shared__ char smem[];  // 32 KB: 32 rows x 1024B, swizzled
    const int tid = threadIdx.x;
    const int wv = tid >> 6, ln = tid & 63;   // wv 0..7
    const int rl = ln & 15, kg = ln >> 4;
    const long long r0 = (long long)blockIdx.x * 32;
    {
        const uint4* src = (const uint4*)(g_ws + r0 * 512);
        #pragma unroll
        for (int q = 0; q < 4; ++q) {
            int idx = q * 512 + tid;       // [0,2048) uint4 = 32 KB
            *(uint4*)(smem + swz1k((unsigned)idx * 16u)) = src[idx];
        }
    }
    __syncthreads();
    f32x4 acc[2][4];
    #pragma unroll
    for (int i = 0; i < 2; ++i)
        #pragma unroll
        for (int jj = 0; jj < 4; ++jj)
            acc[i][jj] = f32x4{0.f, 0.f, 0.f, 0.f};
    for (int kc = 0; kc < 16; ++kc) {
        bf16x8 a[2];
        #pragma unroll
        for (int i = 0; i < 2; ++i) {
            unsigned off = (unsigned)(i * 16 + rl) * 1024u + (unsigned)kc * 64u + (unsigned)kg * 16u;
            a[i] = *(bf16x8*)(smem + swz1k(off));
        }
        bf16x8 bfr[4];
        #pragma unroll
        for (int jj = 0; jj < 4; ++jj) {
            int n = wv * 64 + jj * 16 + rl;
            bfr[jj] = *(const bf16x8*)(Wvb + n * 512 + kc * 32 + kg * 8);
        }
        #pragma unroll
        for (int i = 0; i < 2; ++i)
            #pragma unroll
            for (int jj = 0; jj < 4; ++jj)
                acc[i][jj] = __builtin_amdgcn_mfma_f32_16x16x32_bf16(a[i], bfr[jj], acc[i][jj], 0, 0, 0);
    }
    #pragma unroll
    for (int i = 0; i < 2; ++i)
        #pragma unroll
        for (int jj = 0; jj < 4; ++jj)
            #pragma unroll
            for (int p = 0; p < 4; ++p) {
                int row = i * 16 + kg * 4 + p;
                int col = wv * 64 + jj * 16 + rl;
                out[(r0 + row) * 512 + col] += acc[i][jj][p];
            }
}

extern "C" void kernel_launch(void* const* d_in, const int* in_sizes, int n_in,
                              void* d_out, int out_size, void* d_ws, size_t ws_size,
                              hipStream_t stream)
{
    const float* H  = (const float*)d_in[0];
    const float* F  = (const float*)d_in[1];
    const float* Wq = (const float*)d_in[2];
    const float* Wk = (const float*)d_in[3];
    const float* Wv = (const float*)d_in[4];
    float* out = (float*)d_out;

    unsigned short* Pc  = (unsigned short*)d_ws;       // 16*512*32   = 262144 bf16
    unsigned short* Wvb = Pc + 262144;                 // 512*512     = 262144 bf16
    unsigned short* g   = Wvb + 262144;                // 8192*512    = 4194304 bf16
    (void)in_sizes; (void)n_in; (void)out_size; (void)ws_size;

    prep_kernel<<<dim3(2048), dim3(256), 0, stream>>>(Wq, Wk, Wv, Pc, Wvb);
    attn_main_kernel<<<dim3(2048), dim3(1024), 131840, stream>>>(H, F, Pc, out, g);
    out_gemm_kernel<<<dim3(256), dim3(512), 32768, stream>>>(g, Wvb, out);
}

// Round 20
// 167.826 us; speedup vs baseline: 1.4792x; 1.1536x over previous
//
#include <hip/hip_runtime.h>

typedef __bf16 bf16x8 __attribute__((ext_vector_type(8)));
typedef float f32x4 __attribute__((ext_vector_type(4)));

__device__ __forceinline__ unsigned short f2bf(float f) {
    unsigned int u = __builtin_bit_cast(unsigned int, f);
    u += 0x7fffu + ((u >> 16) & 1u);
    return (unsigned short)(u >> 16);
}
__device__ __forceinline__ float bf2f(unsigned short u) {
    return __builtin_bit_cast(float, (unsigned)u << 16);
}

// XOR swizzle for 1024B-row LDS tiles: byte ^= ((row&7)<<4)
__device__ __forceinline__ unsigned swz1k(unsigned byte) {
    return byte ^ ((byte >> 6) & 0x70u);
}

// Raw barrier: LDS-visibility only; does NOT drain vmcnt.
__device__ __forceinline__ void bar_lgkm() {
    asm volatile("s_waitcnt lgkmcnt(0)\n\ts_barrier" ::: "memory");
}
#define SB() __builtin_amdgcn_sched_barrier(0)

// ---------------- K1 (MFMA version): M = Wq^T Wk -> Pc[kc][j][t] (bf16),
// Pc[((d>>5)*512 + j)*32 + (d&31)] = M[d][j].  256 GEMM blocks = 16x16 grid
// of 32x32 tiles; LDS-staged transposed operand tiles [32][512e] bf16.
// Blocks 256..263: Wv -> bf16 copy.
__global__ __launch_bounds__(256) void prep_kernel(
    const float* __restrict__ Wq, const float* __restrict__ Wk,
    const float* __restrict__ Wv, unsigned short* __restrict__ Pc,
    unsigned short* __restrict__ Wvb)
{
    const int b = blockIdx.x;
    const int tid = threadIdx.x;
    if (b >= 256) {
        // Wv -> bf16: 8 blocks x 256 thr x 32 float4
        const float4* src = (const float4*)Wv;
        #pragma unroll 8
        for (int r = 0; r < 32; ++r) {
            int fl = (b - 256) * 8192 + r * 256 + tid;
            float4 v = src[fl];
            ushort4 o;
            o.x = f2bf(v.x); o.y = f2bf(v.y); o.z = f2bf(v.z); o.w = f2bf(v.w);
            *(ushort4*)(Wvb + fl * 4) = o;
        }
        return;
    }

    extern __shared__ char smem[];
    char* LDSA = smem;            // 32 rows (d) x 1024B (512 e bf16), swizzled
    char* LDSB = smem + 32768;    // 32 rows (j) x 1024B, swizzled

    const int d0 = (b >> 4) * 32;
    const int j0 = (b & 15) * 32;
    const int wv = tid >> 6;      // 0..3
    const int ln = tid & 63;
    const int rl = ln & 15;
    const int kg = ln >> 4;

    // ---- stage transposed tiles: LDSA[dd][e] = Wq[e][d0+dd], LDSB[jj][e] = Wk[e][j0+jj]
    // c = tid>>5 (0..7) -> dd/jj = 4c+k ; e = tid&31 + 32p. Column b16 writes:
    // 32 consecutive-e lanes per row -> 2 lanes/dword/bank (free, m136).
    {
        const int c = tid >> 5;
        const int el = tid & 31;
        #pragma unroll
        for (int p = 0; p < 16; ++p) {
            const int e = p * 32 + el;
            float4 qa = *(const float4*)(Wq + (long long)e * 512 + d0 + c * 4);
            float4 qb = *(const float4*)(Wk + (long long)e * 512 + j0 + c * 4);
            float av[4] = {qa.x, qa.y, qa.z, qa.w};
            float bvv[4] = {qb.x, qb.y, qb.z, qb.w};
            #pragma unroll
            for (int k = 0; k < 4; ++k) {
                unsigned byte = (unsigned)(c * 4 + k) * 1024u + (unsigned)e * 2u;
                *(unsigned short*)(LDSA + swz1k(byte)) = f2bf(av[k]);
                *(unsigned short*)(LDSB + swz1k(byte)) = f2bf(bvv[k]);
            }
        }
    }
    bar_lgkm();

    // ---- GEMM: wave w computes 16x16 frag (df = w>>1, jf = w&1)
    const int df = wv >> 1, jf = wv & 1;
    f32x4 acc = f32x4{0.f, 0.f, 0.f, 0.f};
    #pragma unroll
    for (int kc = 0; kc < 16; ++kc) {
        unsigned cb = (unsigned)kc * 64u + (unsigned)kg * 16u;
        bf16x8 a = *(bf16x8*)(LDSA + swz1k((unsigned)(df * 16 + rl) * 1024u + cb));
        bf16x8 bb = *(bf16x8*)(LDSB + swz1k((unsigned)(jf * 16 + rl) * 1024u + cb));
        acc = __builtin_amdgcn_mfma_f32_16x16x32_bf16(a, bb, acc, 0, 0, 0);
    }
    // C layout: col=lane&15 (j), row=(lane>>4)*4+p (d)
    #pragma unroll
    for (int p = 0; p < 4; ++p) {
        int d = d0 + df * 16 + kg * 4 + p;
        int j = j0 + jf * 16 + rl;
        Pc[((d >> 5) * 512 + j) * 32 + (d & 31)] = f2bf(acc[p]);
    }
}

// issue H column-quarter q (64-row tile, 1024 threads): 2 float4/thread.
__device__ __forceinline__ void issue_q(int q, int tid, const float4* hsrc, float4 (&hq)[2]) {
    #pragma unroll
    for (int r = 0; r < 2; ++r) {
        int flat = r * 1024 + tid;         // [0,2048)
        hq[r] = hsrc[(flat >> 5) * 128 + q * 32 + (flat & 31)];
    }
}

// convert quarter q -> bf16 swizzled HBF (consumes hq)
__device__ __forceinline__ void convert_q(int q, int tid, char* HBF, float4 (&hq)[2]) {
    #pragma unroll
    for (int r = 0; r < 2; ++r) {
        int flat = r * 1024 + tid;
        int row = flat >> 5, ch = flat & 31;
        ushort4 bv;
        bv.x = f2bf(hq[r].x); bv.y = f2bf(hq[r].y);
        bv.z = f2bf(hq[r].z); bv.w = f2bf(hq[r].w);
        *(ushort4*)(HBF + swz1k((unsigned)row * 1024u + (unsigned)(q * 32 + ch) * 8u)) = bv;
    }
}

// GEMM over kc = kcbase..kcbase+3, 2-deep rolling Pc prefetch, per-wave
// j-slice of 32 cols (2 frags). If PREF: issue H quarter at k==1 AFTER that
// iter's Pc issue.
template<bool PREF>
__device__ __forceinline__ void gemm_q(
    int kcbase, int tid, int rl, int kg,
    const unsigned short* bptr, char* HBF,
    bf16x8 (&st0)[2], bf16x8 (&st1)[2],
    f32x4 (&acc)[4][2],
    float4 (&hq)[2], const float4* hsrc, int hq_q)
{
    #pragma unroll
    for (int k = 0; k < 4; ++k) {
        const int kc = kcbase + k;
        bf16x8 bn[2];
        if (kc + 2 < 16) {
            #pragma unroll
            for (int jj = 0; jj < 2; ++jj)
                bn[jj] = *(const bf16x8*)(bptr + (kc + 2) * 16384 + jj * 512);
        }
        if (PREF && k == 1) {
            SB();
            issue_q(hq_q, tid, hsrc, hq);
            SB();
        }
        bf16x8 a[4];
        #pragma unroll
        for (int i = 0; i < 4; ++i) {
            unsigned off = (unsigned)(i * 16 + rl) * 1024u + (unsigned)kc * 64u + (unsigned)kg * 16u;
            a[i] = *(bf16x8*)(HBF + swz1k(off));
        }
        #pragma unroll
        for (int i = 0; i < 4; ++i)
            #pragma unroll
            for (int jj = 0; jj < 2; ++jj)
                acc[i][jj] = __builtin_amdgcn_mfma_f32_16x16x32_bf16(a[i], st0[jj], acc[i][jj], 0, 0, 0);
        #pragma unroll
        for (int jj = 0; jj < 2; ++jj) { st0[jj] = st1[jj]; st1[jj] = bn[jj]; }
    }
}

// ---------------- K2: fused main kernel (r11 structure, empirical best).
// 1 block = 4 batches = 64 H rows, 1024 threads (16 waves, 4/SIMD).
__global__ __launch_bounds__(1024, 4) void attn_main_kernel(
    const float* __restrict__ H, const float* __restrict__ F,
    const unsigned short* __restrict__ Pc,
    float* __restrict__ out, unsigned short* __restrict__ g_ws)
{
    extern __shared__ char smem[];
    char* HBF  = smem;                        // 64 rows x 1024B, swizzled (64 KB)
    char* TBF  = smem + 65536;                // 64 KB
    float* wbuf = (float*)(smem + 131072);    // [4][16]
    float* FL   = (float*)(smem + 131328);    // [64]
    float* LFL  = (float*)(smem + 131584);    // [64]

    const int tid = threadIdx.x;
    const int wv = tid >> 6;                  // 0..15
    const int ln = tid & 63;
    const int rl = ln & 15;
    const int kg = ln >> 4;
    const int blk = blockIdx.x;
    const long long gr0 = (long long)blk * 64;
    const float4* hsrc = (const float4*)(H + gr0 * 512);

    float fval = 0.f;
    if (tid < 64) fval = F[blk * 64 + tid];

    float4 hqA[2], hqB[2];
    issue_q(0, tid, hsrc, hqA);

    // per-wave j-slice: j = wv*32 + jj*16 + rl, jj in {0,1}
    const unsigned short* bptr = Pc + ((wv * 32 + rl) * 32 + kg * 8);
    bf16x8 st0[2], st1[2];
    #pragma unroll
    for (int jj = 0; jj < 2; ++jj) st0[jj] = *(const bf16x8*)(bptr + 0 * 16384 + jj * 512);
    #pragma unroll
    for (int jj = 0; jj < 2; ++jj) st1[jj] = *(const bf16x8*)(bptr + 1 * 16384 + jj * 512);

    issue_q(1, tid, hsrc, hqB);

    if (tid < 64) {
        FL[tid] = fval;
        LFL[tid] = logf(fval + 1e-8f);
    }

    f32x4 acc[4][2];
    #pragma unroll
    for (int i = 0; i < 4; ++i)
        #pragma unroll
        for (int jj = 0; jj < 2; ++jj)
            acc[i][jj] = f32x4{0.f, 0.f, 0.f, 0.f};

    convert_q(0, tid, HBF, hqA);
    bar_lgkm();
    gemm_q<true >(0,  tid, rl, kg, bptr, HBF, st0, st1, acc, hqA, hsrc, 2);
    convert_q(1, tid, HBF, hqB);
    bar_lgkm();
    gemm_q<true >(4,  tid, rl, kg, bptr, HBF, st0, st1, acc, hqB, hsrc, 3);
    convert_q(2, tid, HBF, hqA);
    bar_lgkm();
    gemm_q<false>(8,  tid, rl, kg, bptr, HBF, st0, st1, acc, hqA, hsrc, 0);
    convert_q(3, tid, HBF, hqB);
    bar_lgkm();
    gemm_q<false>(12, tid, rl, kg, bptr, HBF, st0, st1, acc, hqB, hsrc, 0);

    // write T into TBF (C layout: col=lane&15, row=(lane>>4)*4+p)
    #pragma unroll
    for (int i = 0; i < 4; ++i)
        #pragma unroll
        for (int jj = 0; jj < 2; ++jj)
            #pragma unroll
            for (int p = 0; p < 4; ++p) {
                unsigned row = (unsigned)(i * 16 + kg * 4 + p);
                unsigned col = (unsigned)(wv * 32 + jj * 16 + rl);
                *(unsigned short*)(TBF + swz1k(row * 1024u + col * 2u)) = f2bf(acc[i][jj][p]);
            }
    bar_lgkm();   // TBF ready

    // ---- phase 3: waves 0-3: scores+softmax+w ; waves 4-11: residual pool
    if (wv < 4) {
        f32x4 sc0 = f32x4{0.f,0.f,0.f,0.f}, sc1 = sc0, sc2 = sc0, sc3 = sc0;
        __builtin_amdgcn_s_setprio(1);
        #pragma unroll
        for (int kc = 0; kc < 16; ++kc) {
            unsigned off = (unsigned)(wv * 16 + rl) * 1024u + (unsigned)kc * 64u + (unsigned)kg * 16u;
            bf16x8 aT = *(bf16x8*)(TBF + swz1k(off));
            bf16x8 bH = *(bf16x8*)(HBF + swz1k(off));   // H rows as B == H^T
            if ((kc & 3) == 0) sc0 = __builtin_amdgcn_mfma_f32_16x16x32_bf16(aT, bH, sc0, 0, 0, 0);
            else if ((kc & 3) == 1) sc1 = __builtin_amdgcn_mfma_f32_16x16x32_bf16(aT, bH, sc1, 0, 0, 0);
            else if ((kc & 3) == 2) sc2 = __builtin_amdgcn_mfma_f32_16x16x32_bf16(aT, bH, sc2, 0, 0, 0);
            else sc3 = __builtin_amdgcn_mfma_f32_16x16x32_bf16(aT, bH, sc3, 0, 0, 0);
        }
        __builtin_amdgcn_s_setprio(0);
        f32x4 sc;
        #pragma unroll
        for (int p = 0; p < 4; ++p) sc[p] = (sc0[p] + sc1[p]) + (sc2[p] + sc3[p]);

        float bias = LFL[wv * 16 + rl];
        float alpha[4];
        #pragma unroll
        for (int p = 0; p < 4; ++p) {
            float s = sc[p] * 0.044194173824159216f + bias;  // 1/sqrt(512)
            float m = s;
            m = fmaxf(m, __shfl_xor(m, 8));
            m = fmaxf(m, __shfl_xor(m, 4));
            m = fmaxf(m, __shfl_xor(m, 2));
            m = fmaxf(m, __shfl_xor(m, 1));
            float e = expf(s - m);
            float sum = e;
            sum += __shfl_xor(sum, 8);
            sum += __shfl_xor(sum, 4);
            sum += __shfl_xor(sum, 2);
            sum += __shfl_xor(sum, 1);
            alpha[p] = e / sum;
        }
        float part = 0.f;
        #pragma unroll
        for (int p = 0; p < 4; ++p) part += FL[wv * 16 + kg * 4 + p] * alpha[p];
        part += __shfl_xor(part, 16);
        part += __shfl_xor(part, 32);
        if (ln < 16) wbuf[wv * 16 + ln] = part;
    } else if (wv < 12) {
        // residual F-pool: unit = (batch bb, d-half dh); lane covers 4 d
        int u = wv - 4;
        int bb = u >> 1, dh = u & 1;
        const long long Bg = (long long)blk * 4 + bb;
        int d0 = dh * 256 + ln * 4;
        float o[4];
        #pragma unroll
        for (int q = 0; q < 4; ++q) o[q] = 0.f;
        #pragma unroll
        for (int k = 0; k < 16; ++k) {
            unsigned off = (unsigned)(bb * 16 + k) * 1024u + (unsigned)d0 * 2u;
            ushort4 h = *(ushort4*)(HBF + swz1k(off));
            float fk = FL[bb * 16 + k];
            o[0] = fmaf(fk, bf2f(h.x), o[0]); o[1] = fmaf(fk, bf2f(h.y), o[1]);
            o[2] = fmaf(fk, bf2f(h.z), o[2]); o[3] = fmaf(fk, bf2f(h.w), o[3]);
        }
        float4 oa; oa.x = o[0]; oa.y = o[1]; oa.z = o[2]; oa.w = o[3];
        *(float4*)(out + Bg * 512 + d0) = oa;
    }
    bar_lgkm();   // wbuf ready

    // ---- phase 4: g (bf16). 16 waves = 4 batches x 4 d-quarters, from LDS.
    {
        int bb = wv >> 2, q4 = wv & 3;
        const long long Bg = (long long)blk * 4 + bb;
        int d0 = q4 * 128 + ln * 2;
        float g0 = 0.f, g1 = 0.f;
        #pragma unroll
        for (int k = 0; k < 16; ++k) {
            unsigned off = (unsigned)(bb * 16 + k) * 1024u + (unsigned)d0 * 2u;
            ushort2 h = *(ushort2*)(HBF + swz1k(off));
            float wk = wbuf[bb * 16 + k];
            g0 = fmaf(wk, bf2f(h.x), g0); g1 = fmaf(wk, bf2f(h.y), g1);
        }
        ushort2 g2; g2.x = f2bf(g0); g2.y = f2bf(g1);
        *(ushort2*)(g_ws + Bg * 512 + d0) = g2;
    }
}

// ---------------- K3: out += g @ Wv^T   (8192x512 @ 512x512, bf16 MFMA)
// 256 blocks x 32-row tiles, 512 threads = 2 waves/SIMD.
__global__ __launch_bounds__(512) void out_gemm_kernel(
    const unsigned short* __restrict__ g_ws,
    const unsigned short* __restrict__ Wvb,
    float* __restrict__ out)
{
    extern __shared__ char smem[];  // 32 KB: 32 rows x 1024B, swizzled
    const int tid = threadIdx.x;
    const int wv = tid >> 6, ln = tid & 63;   // wv 0..7
    const int rl = ln & 15, kg = ln >> 4;
    const long long r0 = (long long)blockIdx.x * 32;
    {
        const uint4* src = (const uint4*)(g_ws + r0 * 512);
        #pragma unroll
        for (int q = 0; q < 4; ++q) {
            int idx = q * 512 + tid;       // [0,2048) uint4 = 32 KB
            *(uint4*)(smem + swz1k((unsigned)idx * 16u)) = src[idx];
        }
    }
    __syncthreads();
    f32x4 acc[2][4];
    #pragma unroll
    for (int i = 0; i < 2; ++i)
        #pragma unroll
        for (int jj = 0; jj < 4; ++jj)
            acc[i][jj] = f32x4{0.f, 0.f, 0.f, 0.f};
    for (int kc = 0; kc < 16; ++kc) {
        bf16x8 a[2];
        #pragma unroll
        for (int i = 0; i < 2; ++i) {
            unsigned off = (unsigned)(i * 16 + rl) * 1024u + (unsigned)kc * 64u + (unsigned)kg * 16u;
            a[i] = *(bf16x8*)(smem + swz1k(off));
        }
        bf16x8 bfr[4];
        #pragma unroll
        for (int jj = 0; jj < 4; ++jj) {
            int n = wv * 64 + jj * 16 + rl;
            bfr[jj] = *(const bf16x8*)(Wvb + n * 512 + kc * 32 + kg * 8);
        }
        #pragma unroll
        for (int i = 0; i < 2; ++i)
            #pragma unroll
            for (int jj = 0; jj < 4; ++jj)
                acc[i][jj] = __builtin_amdgcn_mfma_f32_16x16x32_bf16(a[i], bfr[jj], acc[i][jj], 0, 0, 0);
    }
    #pragma unroll
    for (int i = 0; i < 2; ++i)
        #pragma unroll
        for (int jj = 0; jj < 4; ++jj)
            #pragma unroll
            for (int p = 0; p < 4; ++p) {
                int row = i * 16 + kg * 4 + p;
                int col = wv * 64 + jj * 16 + rl;
                out[(r0 + row) * 512 + col] += acc[i][jj][p];
            }
}

extern "C" void kernel_launch(void* const* d_in, const int* in_sizes, int n_in,
                              void* d_out, int out_size, void* d_ws, size_t ws_size,
                              hipStream_t stream)
{
    const float* H  = (const float*)d_in[0];
    const float* F  = (const float*)d_in[1];
    const float* Wq = (const float*)d_in[2];
    const float* Wk = (const float*)d_in[3];
    const float* Wv = (const float*)d_in[4];
    float* out = (float*)d_out;

    unsigned short* Pc  = (unsigned short*)d_ws;       // 16*512*32   = 262144 bf16
    unsigned short* Wvb = Pc + 262144;                 // 512*512     = 262144 bf16
    unsigned short* g   = Wvb + 262144;                // 8192*512    = 4194304 bf16
    (void)in_sizes; (void)n_in; (void)out_size; (void)ws_size;

    prep_kernel<<<dim3(264), dim3(256), 65536, stream>>>(Wq, Wk, Wv, Pc, Wvb);
    attn_main_kernel<<<dim3(2048), dim3(1024), 131840, stream>>>(H, F, Pc, out, g);
    out_gemm_kernel<<<dim3(256), dim3(512), 32768, stream>>>(g, Wvb, out);
}